// Round 1
// 2983.769 us; speedup vs baseline: 1.1074x; 1.1074x over previous
//
#include <hip/hip_runtime.h>
#include <stdint.h>

typedef __bf16 bf16;
typedef __bf16 bf16x8 __attribute__((ext_vector_type(8)));
typedef __bf16 bf16x4 __attribute__((ext_vector_type(4)));
typedef float f32x4 __attribute__((ext_vector_type(4)));

#define DEVINL __device__ __forceinline__

constexpr int B_ = 2, S_ = 2048, D_ = 4096, H_ = 32, DH_ = 128, I_ = 11008;
constexpr int T_ = B_ * S_; // 4096 tokens

// async global->LDS, 16B per lane. LDS dest is wave-uniform base + lane*16,
// so callers MUST pass lane-linear lds addresses.
DEVINL void async16(void* lds, const void* g) {
  __builtin_amdgcn_global_load_lds(
      (const __attribute__((address_space(1))) void*)g,
      (__attribute__((address_space(3))) void*)lds, 16, 0, 0);
}

DEVINL f32x4 mfma16(bf16x8 a, bf16x8 b, f32x4 c) {
  return __builtin_amdgcn_mfma_f32_16x16x32_bf16(a, b, c, 0, 0, 0);
}

// raw barrier (no vmcnt/lgkmcnt drain) with compiler memory fences so LDS/global
// accesses cannot be moved across it.
#define GBAR()                                   \
  do {                                           \
    asm volatile("" ::: "memory");               \
    __builtin_amdgcn_s_barrier();                \
    asm volatile("" ::: "memory");               \
  } while (0)

// ---------------------------------------------------------------------------
// fp32 [K,N] -> bf16 [N,K] cast + transpose, 64x64 tiles via LDS
// ---------------------------------------------------------------------------
__global__ __launch_bounds__(256)
void cast_transpose(const float* __restrict__ in, bf16* __restrict__ out,
                    const int K, const int N)
{
  __shared__ float t[64][65];
  const int tx = threadIdx.x & 15, ty = threadIdx.x >> 4;
  const int n0 = blockIdx.x * 64, k0 = blockIdx.y * 64;
#pragma unroll
  for (int j = 0; j < 4; ++j) {
    const int r = ty + j * 16;
    const float4 vv = *(const float4*)&in[(size_t)(k0 + r) * N + n0 + tx * 4];
    t[r][tx * 4 + 0] = vv.x;
    t[r][tx * 4 + 1] = vv.y;
    t[r][tx * 4 + 2] = vv.z;
    t[r][tx * 4 + 3] = vv.w;
  }
  __syncthreads();
#pragma unroll
  for (int j = 0; j < 4; ++j) {
    const int n = ty + j * 16;
    bf16x4 o;
    o[0] = (bf16)t[tx * 4 + 0][n];
    o[1] = (bf16)t[tx * 4 + 1][n];
    o[2] = (bf16)t[tx * 4 + 2][n];
    o[3] = (bf16)t[tx * 4 + 3][n];
    *(bf16x4*)&out[(size_t)(n0 + n) * K + k0 + tx * 4] = o;
  }
}

// ---------------------------------------------------------------------------
// RMSNorm: fp32 [rows, 4096] -> bf16, one block per row
// ---------------------------------------------------------------------------
__global__ __launch_bounds__(256)
void rmsnorm_k(const float* __restrict__ x, const float* __restrict__ w,
               bf16* __restrict__ out)
{
  const int row = blockIdx.x;
  const int tid = threadIdx.x;
  const float* xr = x + (size_t)row * D_;
  float4 v[4];
  float ss = 0.f;
#pragma unroll
  for (int i = 0; i < 4; ++i) {
    v[i] = *(const float4*)&xr[tid * 4 + i * 1024];
    ss += v[i].x * v[i].x + v[i].y * v[i].y + v[i].z * v[i].z + v[i].w * v[i].w;
  }
#pragma unroll
  for (int off = 32; off > 0; off >>= 1) ss += __shfl_xor(ss, off);
  __shared__ float red[4];
  if ((tid & 63) == 0) red[tid >> 6] = ss;
  __syncthreads();
  const float tot = red[0] + red[1] + red[2] + red[3];
  const float sc = rsqrtf(tot * (1.f / D_) + 1e-6f);
#pragma unroll
  for (int i = 0; i < 4; ++i) {
    const float4 wv = *(const float4*)&w[tid * 4 + i * 1024];
    bf16x4 o;
    o[0] = (bf16)(v[i].x * sc * wv.x);
    o[1] = (bf16)(v[i].y * sc * wv.y);
    o[2] = (bf16)(v[i].z * sc * wv.z);
    o[3] = (bf16)(v[i].w * sc * wv.w);
    *(bf16x4*)&out[(size_t)row * D_ + tid * 4 + i * 1024] = o;
  }
}

// ---------------------------------------------------------------------------
// GEMM 256x256 tile, BK=64, 8 waves (2M x 4N, 128x64 C each), 8-phase
// pipelined schedule with counted vmcnt (T2+T3+T4+T5), XCD-swizzled grid.
//
// LDS: 8 regions x 16 KiB = 128 KiB. Region (parity p, which w):
//   w=0: A k[0,32)   w=1: A k[32,64)   w=2: B k[0,32)   w=3: B k[32,64)
// Each region: 256 rows x 32 bf16; 4 chunks (16B) per row; chunk slot c holds
// global chunk c ^ (r&3) ^ ((r>>2)&3)  (bank-spread swizzle, both sides).
//
// Per K-tile t (parity P): 4 phases = (kh,nh) quadrants in order
// (0,0),(0,1),(1,1),(1,0); each phase = {ds_read frags; stage 1 half-tile;
// barrier; 16 MFMA (setprio); barrier}. Region liveness is K-half-staggered,
// so staging K-tile t+2 into region X is issued one phase after X's last
// reader drained (barrier-separated). Single vmcnt(6) per K-tile at phase 4
// guarantees K-tile t+1 fully landed (the 6 in-flight loads are exactly
// {Ak0,Bk0,Ak1}[t+2]). Never vmcnt(0) in the main loop (tail only).
//
// MODE 0: +bias, scatter to q/k/v   MODE 1/3: fp32 = res + acc   MODE 2: bf16 = acc
// ---------------------------------------------------------------------------
template<int MODE>
__global__ __launch_bounds__(512, 2)
void gemm256(const bf16* __restrict__ A, const bf16* __restrict__ BT,
             const int nwgx, const int N, const int K,
             const float* __restrict__ res, const float* __restrict__ bias,
             void* __restrict__ outp)
{
  __shared__ bf16 lds[65536]; // 128 KiB
  const int tid = threadIdx.x;
  const int lane = tid & 63, wave = tid >> 6;
  const int wm = wave >> 2, wn = wave & 3;
  const int quad = lane >> 4, l16 = lane & 15;

  // XCD-aware swizzle (all grids here are multiples of 8)
  const int nwg = (int)gridDim.x;
  const int lin = (int)blockIdx.x;
  const int swz = (lin & 7) * (nwg >> 3) + (lin >> 3);
  const int bx = swz % nwgx, by = swz / nwgx;
  const int m0 = by * 256, n0 = bx * 256;

  const bf16* __restrict__ Ab = A + (size_t)m0 * K;
  const bf16* __restrict__ Bb = BT + (size_t)n0 * K;

  // staging lane geometry: issue is in {0,1}: j = is*512+tid, row r = j>>2,
  // lds slot = j&3, pre-swizzled global chunk g = (j&3)^(r&3)^((r>>2)&3)
  const int r0 = tid >> 2, g0 = (tid & 3) ^ (r0 & 3) ^ ((r0 >> 2) & 3);
  const int jj = 512 + tid;
  const int r1 = jj >> 2, g1 = (jj & 3) ^ (r1 & 3) ^ ((r1 >> 2) & 3);
  const bf16* a0 = Ab + (size_t)r0 * K + g0 * 8;
  const bf16* a1 = Ab + (size_t)r1 * K + g1 * 8;
  const bf16* b0 = Bb + (size_t)r0 * K + g0 * 8;
  const bf16* b1 = Bb + (size_t)r1 * K + g1 * 8;
  const int d0 = tid * 8, d1 = 4096 + tid * 8;

#define STG(reg, p0_, p1_, ke_)                          \
  do {                                                   \
    async16(&lds[(reg) * 8192 + d0], (p0_) + (ke_));     \
    async16(&lds[(reg) * 8192 + d1], (p1_) + (ke_));     \
  } while (0)

#define FRAG(reg, rr_)                                                        \
  (*(const bf16x8*)&lds[(reg) * 8192 +                                        \
      ((rr_) * 4 + (quad ^ ((rr_) & 3) ^ (((rr_) >> 2) & 3))) * 8])

  const f32x4 fz = {0.f, 0.f, 0.f, 0.f};
  f32x4 acc[8][4];
#pragma unroll
  for (int a = 0; a < 8; ++a)
#pragma unroll
    for (int b = 0; b < 4; ++b) acc[a][b] = fz;

  // prologue: K-tile 0 fully {Ak0,Bk0,Ak1,Bk1} + K-tile 1 {Ak0,Bk0,Ak1}
  STG(0, a0, a1, 0);
  STG(2, b0, b1, 0);
  STG(1, a0, a1, 32);
  STG(3, b0, b1, 32);
  STG(4, a0, a1, 64);
  STG(6, b0, b1, 64);
  STG(5, a0, a1, 96);
  asm volatile("s_waitcnt vmcnt(6)" ::: "memory"); // K-tile 0 landed
  GBAR();

  const int nkt = K >> 6;
  bf16x8 af[8], bv[2];

#define MFMACL(J0)                                                      \
  do {                                                                  \
    __builtin_amdgcn_s_setprio(1);                                      \
    _Pragma("unroll")                                                   \
    for (int mt = 0; mt < 8; ++mt) {                                    \
      acc[mt][J0] = mfma16(af[mt], bv[0], acc[mt][J0]);                 \
      acc[mt][J0 + 1] = mfma16(af[mt], bv[1], acc[mt][J0 + 1]);         \
    }                                                                   \
    __builtin_amdgcn_s_setprio(0);                                      \
  } while (0)

  for (int t = 0; t < nkt; ++t) {
    const int P = (t & 1) << 2; // this tile's region group (0 or 4)
    const int Q = 4 - P;        // other parity group
    const bool s1 = (t + 1) < nkt;
    const bool s2 = (t + 2) < nkt;
    const size_t ke1 = (size_t)(t + 1) * 64;
    const size_t ke2 = (size_t)(t + 2) * 64;

    // ---- phase 1: kh=0, n-cols [0,32) ----
#pragma unroll
    for (int mt = 0; mt < 8; ++mt) af[mt] = FRAG(P + 0, wm * 128 + mt * 16 + l16);
#pragma unroll
    for (int nt = 0; nt < 2; ++nt) bv[nt] = FRAG(P + 2, wn * 64 + nt * 16 + l16);
    if (s1) STG(Q + 3, b0, b1, ke1 + 32); // Bk1[t+1] (region dead since t-1.ph4)
    GBAR();
    MFMACL(0);
    GBAR();

    // ---- phase 2: kh=0, n-cols [32,64) ----
#pragma unroll
    for (int nt = 0; nt < 2; ++nt) bv[nt] = FRAG(P + 2, wn * 64 + 32 + nt * 16 + l16);
    if (s2) STG(P + 0, a0, a1, ke2);      // Ak0[t+2] (Ak0[t] dead after ph1)
    GBAR();
    MFMACL(2);
    GBAR();

    // ---- phase 3: kh=1, n-cols [32,64) ----
#pragma unroll
    for (int mt = 0; mt < 8; ++mt) af[mt] = FRAG(P + 1, wm * 128 + mt * 16 + l16);
#pragma unroll
    for (int nt = 0; nt < 2; ++nt) bv[nt] = FRAG(P + 3, wn * 64 + 32 + nt * 16 + l16);
    if (s2) STG(P + 2, b0, b1, ke2);      // Bk0[t+2] (Bk0[t] dead after ph2)
    GBAR();
    MFMACL(2);
    GBAR();

    // ---- phase 4: kh=1, n-cols [0,32) ----
#pragma unroll
    for (int nt = 0; nt < 2; ++nt) bv[nt] = FRAG(P + 3, wn * 64 + nt * 16 + l16);
    if (s2) STG(P + 1, a0, a1, ke2 + 32); // Ak1[t+2] (Ak1[t] dead after ph3)
    // counted wait: the 6 newest loads are {Ak0,Bk0,Ak1}[t+2] -> everything
    // through Bk1[t+1] (i.e. all of K-tile t+1) has landed. Tail: drain.
    if (s2) asm volatile("s_waitcnt vmcnt(6)" ::: "memory");
    else    asm volatile("s_waitcnt vmcnt(0)" ::: "memory");
    GBAR();
    MFMACL(0);
    GBAR();
  }

  // epilogue
#pragma unroll
  for (int mt = 0; mt < 8; ++mt) {
#pragma unroll
    for (int j = 0; j < 4; ++j) {
      const int col = n0 + wn * 64 + j * 16 + l16;
#pragma unroll
      for (int r = 0; r < 4; ++r) {
        const int row = m0 + wm * 128 + mt * 16 + quad * 4 + r;
        float v = acc[mt][j][r];
        if constexpr (MODE == 0) {
          v += bias[col];
          const int b = row >> 11, s = row & (S_ - 1);
          const int which = col >> 12, rr = col & (D_ - 1);
          const int h = rr >> 7, d = rr & (DH_ - 1);
          ((bf16*)outp)[(size_t)which * ((size_t)T_ * D_) +
                        ((size_t)(b * H_ + h) * S_ + s) * DH_ + d] = (bf16)v;
        } else if constexpr (MODE == 1) {
          const size_t idx = (size_t)row * N + col;
          ((float*)outp)[idx] = res[idx] + v;
        } else if constexpr (MODE == 2) {
          ((bf16*)outp)[(size_t)row * N + col] = (bf16)v;
        } else {
          const size_t idx = (size_t)row * N + col;
          ((float*)outp)[idx] = res[idx] + v;
        }
      }
    }
  }
#undef STG
#undef FRAG
#undef MFMACL
}

// ---------------------------------------------------------------------------
// RoPE in-place on q,k [B,H,S,128]; pair (i, i+64), one thread per pair
// ---------------------------------------------------------------------------
__global__ __launch_bounds__(256)
void rope_qk(bf16* __restrict__ q, bf16* __restrict__ kk,
             const int* __restrict__ pos)
{
  const int idx = blockIdx.x * 256 + threadIdx.x; // B*H*S*64
  const int i = idx & 63;
  const int s = (idx >> 6) & (S_ - 1);
  const int bh = idx >> 17;
  const int b = bh >> 5;
  const int p = pos[b * S_ + s];
  const float fr = exp2f((float)i * (-13.287712379549449f / 64.f));
  const float ang = (float)p * fr;
  const float cs = cosf(ang), sn = sinf(ang);
  const size_t base = ((size_t)bh * S_ + s) * DH_ + i;
  {
    const float x1 = (float)q[base], x2 = (float)q[base + 64];
    q[base]      = (bf16)(x1 * cs - x2 * sn);
    q[base + 64] = (bf16)(x2 * cs + x1 * sn);
  }
  {
    const float x1 = (float)kk[base], x2 = (float)kk[base + 64];
    kk[base]      = (bf16)(x1 * cs - x2 * sn);
    kk[base + 64] = (bf16)(x2 * cs + x1 * sn);
  }
}

// ---------------------------------------------------------------------------
// V [bh, s, d] -> VT [bh, d, s], 64x64 tiles
// ---------------------------------------------------------------------------
__global__ __launch_bounds__(256)
void transpose_v(const bf16* __restrict__ in, bf16* __restrict__ out)
{
  __shared__ bf16 t[64][72];
  const int tx = threadIdx.x & 15, ty = threadIdx.x >> 4;
  const int bh = blockIdx.z;
  const int s0 = blockIdx.x * 64, d0 = blockIdx.y * 64;
#pragma unroll
  for (int j = 0; j < 4; ++j) {
    const int r = ty + j * 16;
    const bf16x4 vv = *(const bf16x4*)&in[((size_t)bh * S_ + s0 + r) * DH_ + d0 + tx * 4];
    t[r][tx * 4 + 0] = vv[0];
    t[r][tx * 4 + 1] = vv[1];
    t[r][tx * 4 + 2] = vv[2];
    t[r][tx * 4 + 3] = vv[3];
  }
  __syncthreads();
#pragma unroll
  for (int j = 0; j < 4; ++j) {
    const int d = ty + j * 16;
    bf16x4 o;
    o[0] = t[tx * 4 + 0][d];
    o[1] = t[tx * 4 + 1][d];
    o[2] = t[tx * 4 + 2][d];
    o[3] = t[tx * 4 + 3][d];
    *(bf16x4*)&out[((size_t)bh * DH_ + d0 + d) * S_ + s0 + tx * 4] = o;
  }
}

// ---------------------------------------------------------------------------
// Flash attention, causal. Block = one (bh, 128-row q-tile); 4 waves,
// wave w owns q rows [w*32, w*32+32). K-tiles of 64. P round-trips via LDS.
// ---------------------------------------------------------------------------
__global__ __launch_bounds__(256)
void flash_attn(const bf16* __restrict__ q, const bf16* __restrict__ kv,
                const bf16* __restrict__ vt, bf16* __restrict__ out)
{
  __shared__ bf16 Kl[64 * 128];  // [kk][d], 16-chunk XOR swizzle
  __shared__ bf16 Vl[128 * 64];  // [d][kk], 8-chunk XOR swizzle
  __shared__ bf16 Pl[128 * 64];  // [qr][kk], 8-chunk XOR swizzle (wave-private rows)
  const int tid = threadIdx.x, lane = tid & 63, wave = tid >> 6;
  const int quad = lane >> 4, l16 = lane & 15;
  const int qt = blockIdx.x, bh = blockIdx.y;
  const int qbase = qt * 128;
  const float scale = 0.08838834764831845f; // 128^-0.5

  bf16x8 qf[2][4];
#pragma unroll
  for (int mt = 0; mt < 2; ++mt) {
    const size_t rb = ((size_t)bh * S_ + qbase + wave * 32 + mt * 16 + l16) * DH_;
#pragma unroll
    for (int dk = 0; dk < 4; ++dk)
      qf[mt][dk] = *(const bf16x8*)&q[rb + dk * 32 + quad * 8];
  }

  const f32x4 fz = {0.f, 0.f, 0.f, 0.f};
  f32x4 o[2][8];
#pragma unroll
  for (int a = 0; a < 2; ++a)
#pragma unroll
    for (int b = 0; b < 8; ++b) o[a][b] = fz;
  float mi[2][4], li[2][4];
#pragma unroll
  for (int a = 0; a < 2; ++a)
#pragma unroll
    for (int r = 0; r < 4; ++r) { mi[a][r] = -1e30f; li[a][r] = 0.f; }

  const int nkt = 2 * qt + 2;
  for (int kt = 0; kt < nkt; ++kt) {
#pragma unroll
    for (int i = 0; i < 4; ++i) {
      const int j = i * 256 + tid;
      { const int r = j >> 4, c = (j & 15) ^ (r & 15);
        async16(&Kl[j * 8], &kv[((size_t)bh * S_ + kt * 64 + r) * DH_ + c * 8]); }
      { const int r = j >> 3, c = (j & 7) ^ (r & 7);
        async16(&Vl[j * 8], &vt[((size_t)bh * DH_ + r) * S_ + kt * 64 + c * 8]); }
    }
    __syncthreads();

    // S = Q K^T  (sc tiles: 2 m x 4 n of 16x16)
    f32x4 sc4[2][4];
#pragma unroll
    for (int a = 0; a < 2; ++a)
#pragma unroll
      for (int b = 0; b < 4; ++b) sc4[a][b] = fz;
#pragma unroll
    for (int dk = 0; dk < 4; ++dk) {
      bf16x8 kf[4];
#pragma unroll
      for (int nt = 0; nt < 4; ++nt) {
        const int kkr = nt * 16 + l16;
        kf[nt] = *(const bf16x8*)&Kl[((kkr * 16) + ((dk * 4 + quad) ^ (kkr & 15))) * 8];
      }
#pragma unroll
      for (int mt = 0; mt < 2; ++mt)
#pragma unroll
        for (int nt = 0; nt < 4; ++nt)
          sc4[mt][nt] = mfma16(qf[mt][dk], kf[nt], sc4[mt][nt]);
    }

    const bool domask = (kt >= 2 * qt);
    float mnew[2][4], al[2][4];
#pragma unroll
    for (int mt = 0; mt < 2; ++mt)
#pragma unroll
      for (int r = 0; r < 4; ++r) {
        float rm = -1e30f;
#pragma unroll
        for (int nt = 0; nt < 4; ++nt) {
          float vv = sc4[mt][nt][r] * scale;
          if (domask) {
            const int kg = kt * 64 + nt * 16 + l16;
            const int qg = qbase + wave * 32 + mt * 16 + quad * 4 + r;
            if (kg > qg) vv = -1e30f;
          }
          sc4[mt][nt][r] = vv;
          rm = fmaxf(rm, vv);
        }
#pragma unroll
        for (int off = 8; off > 0; off >>= 1) rm = fmaxf(rm, __shfl_xor(rm, off));
        const float mn = fmaxf(mi[mt][r], rm);
        mnew[mt][r] = mn;
        al[mt][r] = __expf(mi[mt][r] - mn);
        mi[mt][r] = mn;
      }
#pragma unroll
    for (int mt = 0; mt < 2; ++mt)
#pragma unroll
      for (int r = 0; r < 4; ++r) {
        float lsum = 0.f;
        const int qr = wave * 32 + mt * 16 + quad * 4 + r;
#pragma unroll
        for (int nt = 0; nt < 4; ++nt) {
          const float p = __expf(sc4[mt][nt][r] - mnew[mt][r]);
          lsum += p;
          const int kk = nt * 16 + l16;
          Pl[((qr * 8) + ((kk >> 3) ^ (qr & 7))) * 8 + (kk & 7)] = (bf16)p;
        }
#pragma unroll
        for (int off = 8; off > 0; off >>= 1) lsum += __shfl_xor(lsum, off);
        li[mt][r] = li[mt][r] * al[mt][r] + lsum;
      }
#pragma unroll
    for (int mt = 0; mt < 2; ++mt)
#pragma unroll
      for (int nt = 0; nt < 8; ++nt)
#pragma unroll
        for (int r = 0; r < 4; ++r) o[mt][nt][r] *= al[mt][r];

    // O += P V
#pragma unroll
    for (int dk2 = 0; dk2 < 2; ++dk2) {
      bf16x8 pf[2];
#pragma unroll
      for (int mt = 0; mt < 2; ++mt) {
        const int m = wave * 32 + mt * 16 + l16;
        pf[mt] = *(const bf16x8*)&Pl[((m * 8) + ((dk2 * 4 + quad) ^ (m & 7))) * 8];
      }
#pragma unroll
      for (int nt = 0; nt < 8; ++nt) {
        const int d = nt * 16 + l16;
        const bf16x8 vf = *(const bf16x8*)&Vl[((d * 8) + ((dk2 * 4 + quad) ^ (d & 7))) * 8];
#pragma unroll
        for (int mt = 0; mt < 2; ++mt)
          o[mt][nt] = mfma16(pf[mt], vf, o[mt][nt]);
      }
    }
    __syncthreads();
  }

  const int b = bh >> 5, h = bh & 31;
#pragma unroll
  for (int mt = 0; mt < 2; ++mt)
#pragma unroll
    for (int r = 0; r < 4; ++r) {
      const float inv = 1.f / li[mt][r];
      const int qg = qbase + wave * 32 + mt * 16 + quad * 4 + r;
#pragma unroll
      for (int nt = 0; nt < 8; ++nt) {
        const int d = nt * 16 + l16;
        out[((size_t)b * S_ + qg) * D_ + h * DH_ + d] = (bf16)(o[mt][nt][r] * inv);
      }
    }
}

// ---------------------------------------------------------------------------
// SwiGLU: act[m,n] = silu(gu[m,n]) * gu[m,n+I], 8 elems/thread
// ---------------------------------------------------------------------------
__global__ __launch_bounds__(256)
void silu_mul(const bf16* __restrict__ gu, bf16* __restrict__ act)
{
  const size_t idx = ((size_t)blockIdx.x * 256 + threadIdx.x) * 8;
  const size_t m = idx / I_;
  const size_t n = idx - m * I_;
  const bf16x8 g = *(const bf16x8*)&gu[m * (size_t)(2 * I_) + n];
  const bf16x8 u = *(const bf16x8*)&gu[m * (size_t)(2 * I_) + n + I_];
  bf16x8 r;
#pragma unroll
  for (int c = 0; c < 8; ++c) {
    const float gf = (float)g[c], uf = (float)u[c];
    r[c] = (bf16)(gf / (1.f + __expf(-gf)) * uf);
  }
  *(bf16x8*)&act[idx] = r;
}

// ---------------------------------------------------------------------------
extern "C" void kernel_launch(void* const* d_in, const int* in_sizes, int n_in,
                              void* d_out, int out_size, void* d_ws, size_t ws_size,
                              hipStream_t stream)
{
  const float* hidden  = (const float*)d_in[0];
  const int*   pos     = (const int*)d_in[1];
  const float* ln1_w   = (const float*)d_in[2];
  const float* w_qkv   = (const float*)d_in[3];
  const float* b_qkv   = (const float*)d_in[4];
  const float* w_o     = (const float*)d_in[5];
  const float* ln2_w   = (const float*)d_in[6];
  const float* w_gu    = (const float*)d_in[7];
  const float* w_down  = (const float*)d_in[8];

  char* ws = (char*)d_ws;
  const size_t off_wqkvT = 0;                                   // bf16 [12288,4096]
  const size_t off_woT   = off_wqkvT + (size_t)12288 * 4096 * 2;
  const size_t off_wguT  = off_woT   + (size_t)4096 * 4096 * 2; // bf16 [22016,4096]
  const size_t off_wdT   = off_wguT  + (size_t)22016 * 4096 * 2;// bf16 [4096,11008]
  const size_t off_xn    = off_wdT   + (size_t)4096 * 11008 * 2;// bf16 [4096,4096] (reused ln2)
  const size_t off_q     = off_xn    + (size_t)4096 * 4096 * 2; // bf16 [B,H,S,128]
  const size_t off_k     = off_q     + (size_t)16777216 * 2;
  const size_t off_v     = off_k     + (size_t)16777216 * 2;
  const size_t off_vt    = off_v     + (size_t)16777216 * 2;
  const size_t off_ao    = off_vt    + (size_t)16777216 * 2;    // bf16 [T,D]
  const size_t off_h2    = off_ao    + (size_t)16777216 * 2;    // fp32 [T,D]
  const size_t off_gu    = off_h2    + (size_t)4096 * 4096 * 4; // bf16 [T,22016]
  const size_t off_act   = off_q;   // q/k/v/vt dead by MLP time; bf16 [T,11008]

  bf16* wqkvT = (bf16*)(ws + off_wqkvT);
  bf16* woT   = (bf16*)(ws + off_woT);
  bf16* wguT  = (bf16*)(ws + off_wguT);
  bf16* wdT   = (bf16*)(ws + off_wdT);
  bf16* xn    = (bf16*)(ws + off_xn);
  bf16* qb    = (bf16*)(ws + off_q);
  bf16* kb    = (bf16*)(ws + off_k);
  bf16* vb    = (bf16*)(ws + off_v);
  bf16* vtb   = (bf16*)(ws + off_vt);
  bf16* aob   = (bf16*)(ws + off_ao);
  float* h2   = (float*)(ws + off_h2);
  bf16* gub   = (bf16*)(ws + off_gu);
  bf16* actb  = (bf16*)(ws + off_act);

  // 1) weights: fp32 [K,N] -> bf16 [N,K]
  cast_transpose<<<dim3(12288/64, 4096/64), 256, 0, stream>>>(w_qkv, wqkvT, 4096, 12288);
  cast_transpose<<<dim3(4096/64, 4096/64),  256, 0, stream>>>(w_o,   woT,   4096, 4096);
  cast_transpose<<<dim3(22016/64, 4096/64), 256, 0, stream>>>(w_gu,  wguT,  4096, 22016);
  cast_transpose<<<dim3(4096/64, 11008/64), 256, 0, stream>>>(w_down,wdT,  11008, 4096);

  // 2) ln1
  rmsnorm_k<<<T_, 256, 0, stream>>>(hidden, ln1_w, xn);

  // 3) qkv = xn @ w_qkv + b, scatter to q/k/v [B,H,S,128]
  gemm256<0><<<dim3((12288/256) * (T_/256)), 512, 0, stream>>>(xn, wqkvT, 12288/256,
                                                               12288, 4096,
                                                               nullptr, b_qkv, qb);
  // 4) rope on q,k
  rope_qk<<<(B_*H_*S_*64)/256, 256, 0, stream>>>(qb, kb, pos);

  // 5) v -> v^T
  transpose_v<<<dim3(S_/64, DH_/64, B_*H_), 256, 0, stream>>>(vb, vtb);

  // 6) attention
  flash_attn<<<dim3(S_/128, B_*H_), 256, 0, stream>>>(qb, kb, vtb, aob);

  // 7) h2 = hidden + attn_out @ w_o
  gemm256<1><<<dim3((4096/256) * (T_/256)), 512, 0, stream>>>(aob, woT, 4096/256,
                                                              4096, 4096,
                                                              hidden, nullptr, h2);
  // 8) ln2
  rmsnorm_k<<<T_, 256, 0, stream>>>(h2, ln2_w, xn);

  // 9) gu = xn @ w_gate_up
  gemm256<2><<<dim3((22016/256) * (T_/256)), 512, 0, stream>>>(xn, wguT, 22016/256,
                                                               22016, 4096,
                                                               nullptr, nullptr, gub);
  // 10) act = silu(g) * u
  silu_mul<<<(T_*(size_t)I_)/8/256, 256, 0, stream>>>(gub, actb);

  // 11) out = h2 + act @ w_down
  gemm256<3><<<dim3((4096/256) * (T_/256)), 512, 0, stream>>>(actb, wdT, 4096/256,
                                                              4096, 11008,
                                                              h2, nullptr, (float*)d_out);
}